// Round 7
// baseline (459.999 us; speedup 1.0000x reference)
//
#include <hip/hip_runtime.h>
#include <cstdint>
#include <cmath>

#define DH 64
#define SQB 2048
#define SKVB 1024
#define DE 512
#define TQ 32

typedef _Float16 f16;
typedef _Float16 f16x8 __attribute__((ext_vector_type(8)));
typedef float f32x4 __attribute__((ext_vector_type(4)));

// ---------------------------------------------------------------------------
// Split fp32 -> (hi, lo) fp16 pair, optional pre-scale.
// ---------------------------------------------------------------------------
__global__ __launch_bounds__(256)
void split_f16(const float* __restrict__ in, f16* __restrict__ hi,
               f16* __restrict__ lo, int n4, float scale) {
  const int i = blockIdx.x * 256 + threadIdx.x;
  if (i >= n4) return;
  float4 v = ((const float4*)in)[i];
  v.x *= scale; v.y *= scale; v.z *= scale; v.w *= scale;
  f16 h0 = (f16)v.x, h1 = (f16)v.y, h2 = (f16)v.z, h3 = (f16)v.w;
  f16 l0 = (f16)(v.x - (float)h0), l1 = (f16)(v.y - (float)h1);
  f16 l2 = (f16)(v.z - (float)h2), l3 = (f16)(v.w - (float)h3);
  f16 hb[4] = {h0, h1, h2, h3};
  f16 lb[4] = {l0, l1, l2, l3};
  ((uint2*)hi)[i] = *(const uint2*)hb;
  ((uint2*)lo)[i] = *(const uint2*)lb;
}

// ---------------------------------------------------------------------------
// MFMA f16 GEMM (validated R4/R5 core). OUT=0: C fp32. OUT=1: split-f16 pair.
// ---------------------------------------------------------------------------
template <int NSPLIT, int OUT>
__global__ __launch_bounds__(256, 2)
void gemm_f16(const f16* __restrict__ Ah, const f16* __restrict__ Al,
              const f16* __restrict__ Wh, const f16* __restrict__ Wl,
              const float* __restrict__ bias, float* __restrict__ C,
              f16* __restrict__ Ch, f16* __restrict__ Cl,
              int M, int N, int K, float inv, float oscale) {
  __shared__ f16 smem[(NSPLIT == 3 ? 4 : 2) * 4096];
  f16* As  = smem;
  f16* Als = (NSPLIT == 3) ? smem + 4096 : nullptr;
  f16* Ws  = smem + (NSPLIT == 3 ? 8192 : 4096);
  f16* Wls = (NSPLIT == 3) ? smem + 12288 : nullptr;

  const int tid = threadIdx.x;
  const int w = tid >> 6;
  const int l = tid & 63;
  const int wm = w >> 1, wn = w & 1;
  const int m0 = blockIdx.y * 128;
  const int n0 = blockIdx.x * 128;

  const int srow = tid >> 2;
  const int schk = tid & 3;
  const f16* pA  = Ah + (size_t)(m0 + srow) * K + schk * 8;
  const f16* pW  = Wh + (size_t)(n0 + srow) * K + schk * 8;
  const f16* pAl = (NSPLIT == 3) ? Al + (size_t)(m0 + srow) * K + schk * 8 : nullptr;
  const f16* pWl = (NSPLIT == 3) ? Wl + (size_t)(n0 + srow) * K + schk * 8 : nullptr;
  const size_t rowskip = (size_t)64 * K;

  const int d0 = srow * 32 + ((schk ^ (srow & 3)) * 8);
  const int fbase = (l & 15) * 32 + (((l >> 4) ^ (l & 3)) * 8);
  const int fA = wm * 2048 + fbase;
  const int fW = wn * 2048 + fbase;

  f32x4 acc[4][4] = {};
  uint4 rA0, rA1, rW0, rW1, rAl0, rAl1, rWl0, rWl1;

  rA0 = *(const uint4*)(pA);            rA1 = *(const uint4*)(pA + rowskip);
  rW0 = *(const uint4*)(pW);            rW1 = *(const uint4*)(pW + rowskip);
  if constexpr (NSPLIT == 3) {
    rAl0 = *(const uint4*)(pAl);        rAl1 = *(const uint4*)(pAl + rowskip);
    rWl0 = *(const uint4*)(pWl);        rWl1 = *(const uint4*)(pWl + rowskip);
  }

  for (int k0 = 0; k0 < K; k0 += 32) {
    __syncthreads();
    *(uint4*)&As[d0] = rA0;  *(uint4*)&As[d0 + 2048] = rA1;
    *(uint4*)&Ws[d0] = rW0;  *(uint4*)&Ws[d0 + 2048] = rW1;
    if constexpr (NSPLIT == 3) {
      *(uint4*)&Als[d0] = rAl0;  *(uint4*)&Als[d0 + 2048] = rAl1;
      *(uint4*)&Wls[d0] = rWl0;  *(uint4*)&Wls[d0 + 2048] = rWl1;
    }
    __syncthreads();

    if (k0 + 32 < K) {
      rA0 = *(const uint4*)(pA + k0 + 32);  rA1 = *(const uint4*)(pA + rowskip + k0 + 32);
      rW0 = *(const uint4*)(pW + k0 + 32);  rW1 = *(const uint4*)(pW + rowskip + k0 + 32);
      if constexpr (NSPLIT == 3) {
        rAl0 = *(const uint4*)(pAl + k0 + 32); rAl1 = *(const uint4*)(pAl + rowskip + k0 + 32);
        rWl0 = *(const uint4*)(pWl + k0 + 32); rWl1 = *(const uint4*)(pWl + rowskip + k0 + 32);
      }
    }

    f16x8 ah[4], wh[4], al[4], wl[4];
#pragma unroll
    for (int i = 0; i < 4; ++i) ah[i] = *(const f16x8*)&As[fA + i * 512];
#pragma unroll
    for (int j = 0; j < 4; ++j) wh[j] = *(const f16x8*)&Ws[fW + j * 512];
    if constexpr (NSPLIT == 3) {
#pragma unroll
      for (int i = 0; i < 4; ++i) al[i] = *(const f16x8*)&Als[fA + i * 512];
#pragma unroll
      for (int j = 0; j < 4; ++j) wl[j] = *(const f16x8*)&Wls[fW + j * 512];
    }

#pragma unroll
    for (int i = 0; i < 4; ++i)
#pragma unroll
      for (int j = 0; j < 4; ++j)
        acc[i][j] = __builtin_amdgcn_mfma_f32_16x16x32_f16(ah[i], wh[j], acc[i][j], 0, 0, 0);
    if constexpr (NSPLIT == 3) {
#pragma unroll
      for (int i = 0; i < 4; ++i)
#pragma unroll
        for (int j = 0; j < 4; ++j)
          acc[i][j] = __builtin_amdgcn_mfma_f32_16x16x32_f16(ah[i], wl[j], acc[i][j], 0, 0, 0);
#pragma unroll
      for (int i = 0; i < 4; ++i)
#pragma unroll
        for (int j = 0; j < 4; ++j)
          acc[i][j] = __builtin_amdgcn_mfma_f32_16x16x32_f16(al[i], wh[j], acc[i][j], 0, 0, 0);
    }
  }

  const int rr = (l >> 4) * 4;
  const int cc = l & 15;
#pragma unroll
  for (int j = 0; j < 4; ++j) {
    const int n = n0 + wn * 64 + j * 16 + cc;
    const float bv = bias[n];
#pragma unroll
    for (int i = 0; i < 4; ++i) {
      const int m = m0 + wm * 64 + i * 16 + rr;
#pragma unroll
      for (int r = 0; r < 4; ++r) {
        const float val = acc[i][j][r] * inv + bv;
        if constexpr (OUT == 0) {
          C[(size_t)(m + r) * N + n] = val;
        } else {
          const float sv = val * oscale;
          const f16 hh = (f16)sv;
          const f16 ll = (f16)(sv - (float)hh);
          Ch[(size_t)(m + r) * N + n] = hh;
          Cl[(size_t)(m + r) * N + n] = ll;
        }
      }
    }
  }
}

// ---------------------------------------------------------------------------
// Fused sparse attention v6: 8 waves / 512 thr, TQ=32 rows per block.
// Wave w: kv quarter wq=w&3, row group rg=w>>2 (rows rg*16 + (l&15)).
// Wave pairs (w, w+4) read the SAME K quarter -> L1/L2 reuse.
// S[t][r] = s_raw[row][kv = wq*256 + t*16 + (l>>4)*4 + r], s_raw = 4096*s.
// S keeps RAW scores; selection done in s-space (identical semantics:
// fast-path p==1.0 <=> s==m); exp2 only for Z/H and selected PV entries.
// ---------------------------------------------------------------------------
__global__ __launch_bounds__(512, 4)
void attn_v6(const f16* __restrict__ qhb, const f16* __restrict__ qlb,
             const f16* __restrict__ khb, const f16* __restrict__ klb,
             const float* __restrict__ vb, f16* __restrict__ ob) {
  __shared__ float pM[4][TQ], pZ[4][TQ], pH[4][TQ], pC[4][TQ];
  __shared__ int cnt[16][TQ];
  __shared__ int lkv[TQ][40];
  __shared__ float lpv[TQ][40];
  __shared__ int lcnt[TQ];
  __shared__ int slowflag;

  const int phys = blockIdx.x;
  const int bid = (phys & 7) * 512 + (phys >> 3);   // batch -> XCD, bijective
  const int qt = bid & 63;
  const int h  = (bid >> 6) & 7;
  const int b  = bid >> 9;
  const int tid = threadIdx.x;
  const int w  = tid >> 6;
  const int wq = w & 3;
  const int rg = w >> 2;
  const int l  = tid & 63;
  const int q16 = l & 15;
  const int row = rg * 16 + q16;
  const int g = l >> 4;

  if (tid == 0) slowflag = 0;

  // ---- Q fragments (B operand)
  const size_t qoff = (size_t)(b * SQB + qt * TQ + row) * DE + h * DH + g * 8;
  const f16x8 qf_h0 = *(const f16x8*)(qhb + qoff);
  const f16x8 qf_h1 = *(const f16x8*)(qhb + qoff + 32);
  const f16x8 qf_l0 = *(const f16x8*)(qlb + qoff);
  const f16x8 qf_l1 = *(const f16x8*)(qlb + qoff + 32);

  // ---- K pointers (A operand) — wave pairs share the same stream
  const size_t koff = (size_t)(b * SKVB + wq * 256 + q16) * DE + h * DH + g * 8;
  const f16* kp  = khb + koff;
  const f16* klp = klb + koff;

  f32x4 S[16];
#pragma unroll
  for (int i = 0; i < 16; ++i) S[i] = (f32x4){0.f, 0.f, 0.f, 0.f};

  float mx = -INFINITY;
  f16x8 ka0 = *(const f16x8*)(kp);
  f16x8 ka1 = *(const f16x8*)(kp + 32);
  f16x8 kb0 = *(const f16x8*)(klp);
  f16x8 kb1 = *(const f16x8*)(klp + 32);
#pragma unroll
  for (int t = 0; t < 16; ++t) {
    f16x8 na0, na1, nb0, nb1;
    if (t < 15) {
      na0 = *(const f16x8*)(kp + 8192);
      na1 = *(const f16x8*)(kp + 8192 + 32);
      nb0 = *(const f16x8*)(klp + 8192);
      nb1 = *(const f16x8*)(klp + 8192 + 32);
      kp += 8192; klp += 8192;
    }
    // two independent 3-chains, folded at the end (halves dep latency)
    f32x4 sb = (f32x4){0.f, 0.f, 0.f, 0.f};
    S[t] = __builtin_amdgcn_mfma_f32_16x16x32_f16(ka0, qf_h0, S[t], 0, 0, 0);
    sb   = __builtin_amdgcn_mfma_f32_16x16x32_f16(ka1, qf_h1, sb,   0, 0, 0);
    S[t] = __builtin_amdgcn_mfma_f32_16x16x32_f16(ka0, qf_l0, S[t], 0, 0, 0);
    sb   = __builtin_amdgcn_mfma_f32_16x16x32_f16(ka1, qf_l1, sb,   0, 0, 0);
    S[t] = __builtin_amdgcn_mfma_f32_16x16x32_f16(kb0, qf_h0, S[t], 0, 0, 0);
    sb   = __builtin_amdgcn_mfma_f32_16x16x32_f16(kb1, qf_h1, sb,   0, 0, 0);
    S[t][0] += sb[0]; S[t][1] += sb[1]; S[t][2] += sb[2]; S[t][3] += sb[3];
    // fold row-max (VALU, overlaps next iteration's MFMAs)
    mx = fmaxf(mx, fmaxf(fmaxf(S[t][0], S[t][1]), fmaxf(S[t][2], S[t][3])));
    if (t < 15) { ka0 = na0; ka1 = na1; kb0 = nb0; kb1 = nb1; }
  }

  // ---- P1: block row max
  mx = fmaxf(mx, __shfl_xor(mx, 16));
  mx = fmaxf(mx, __shfl_xor(mx, 32));
  if (g == 0) pM[wq][row] = mx;
  __syncthreads();
  const float m = fmaxf(fmaxf(pM[0][row], pM[1][row]), fmaxf(pM[2][row], pM[3][row]));

  // ---- P2: Z, H, count(s==m); S stays raw
  const float C2 = 1.44269504f / 4096.0f;
  float Zl = 0.f, Hl = 0.f;
  int cl = 0;
#pragma unroll
  for (int t = 0; t < 16; ++t)
#pragma unroll
    for (int r = 0; r < 4; ++r) {
      const float sv = S[t][r] - m;
      const float p = __builtin_amdgcn_exp2f(sv * C2);
      Zl += p;
      Hl = fmaf(p, sv, Hl);
      cl += (S[t][r] == m) ? 1 : 0;
    }
  cnt[wq * 4 + g][row] = cl;
  float clf = (float)cl;
  Zl += __shfl_xor(Zl, 16); Zl += __shfl_xor(Zl, 32);
  Hl += __shfl_xor(Hl, 16); Hl += __shfl_xor(Hl, 32);
  clf += __shfl_xor(clf, 16); clf += __shfl_xor(clf, 32);
  if (g == 0) { pZ[wq][row] = Zl; pH[wq][row] = Hl; pC[wq][row] = clf; }
  __syncthreads();   // barrier A

  const float Z = (pZ[0][row] + pZ[1][row]) + (pZ[2][row] + pZ[3][row]);
  const float Hraw = (pH[0][row] + pH[1][row]) + (pH[2][row] + pH[3][row]);
  const float c1 = (pC[0][row] + pC[1][row]) + (pC[2][row] + pC[3][row]);
  const float E = __logf(Z) - (Hraw * (1.0f / 4096.0f)) / Z;
  int tk = (int)(32.0f * (1.0f - E));
  tk = tk < 1 ? 1 : (tk > 32 ? 32 : tk);

  float thr = m, cur = m, rem = (float)tk;
  bool pend = !(c1 >= rem);
  const bool rowSlow = pend;
  if (pend) { rem -= c1; slowflag = 1; }
  __syncthreads();   // barrier B: slowflag settled; cnt visible

  // ---- slow path (rare), block-uniform control via slowflag
  bool entered = false;
  while (true) {
    if (slowflag == 0) break;
    entered = true;
    __syncthreads();
    if (tid == 0) slowflag = 0;
    float lmx = -INFINITY;
#pragma unroll
    for (int t = 0; t < 16; ++t)
#pragma unroll
      for (int r = 0; r < 4; ++r) {
        const float s = S[t][r];
        lmx = (s < cur) ? fmaxf(lmx, s) : lmx;
      }
    lmx = fmaxf(lmx, __shfl_xor(lmx, 16));
    lmx = fmaxf(lmx, __shfl_xor(lmx, 32));
    if (g == 0) pM[wq][row] = lmx;
    __syncthreads();
    const float cand = fmaxf(fmaxf(pM[0][row], pM[1][row]), fmaxf(pM[2][row], pM[3][row]));
    float cf = 0.f;
#pragma unroll
    for (int t = 0; t < 16; ++t)
#pragma unroll
      for (int r = 0; r < 4; ++r) cf += (S[t][r] == cand) ? 1.f : 0.f;
    cf += __shfl_xor(cf, 16); cf += __shfl_xor(cf, 32);
    if (g == 0) pC[wq][row] = cf;
    __syncthreads();
    const float c2 = (pC[0][row] + pC[1][row]) + (pC[2][row] + pC[3][row]);
    if (pend) {
      if (c2 >= rem) { thr = cand; pend = false; }
      else { rem -= c2; cur = cand; if (g == 0 && q16 == 0) slowflag = 1; }
      if (pend) slowflag = 1;
    }
    __syncthreads();
  }
  if (entered) {
    if (rowSlow) {
      int ns = 0;
#pragma unroll
      for (int t = 0; t < 16; ++t)
#pragma unroll
        for (int r = 0; r < 4; ++r) ns += (S[t][r] >= thr) ? 1 : 0;
      cnt[wq * 4 + g][row] = ns;
    }
    __syncthreads();
  }

  // ---- append selected (kv, p) per row, deterministic group order
  {
    int off = 0;
    const int me = wq * 4 + g;
#pragma unroll
    for (int gi = 0; gi < 15; ++gi)
      if (gi < me) off += cnt[gi][row];
    const int nsel = cnt[me][row];
    if (me == 15) lcnt[row] = off + nsel;
#pragma unroll
    for (int t = 0; t < 16; ++t)
#pragma unroll
      for (int r = 0; r < 4; ++r) {
        if (S[t][r] >= thr) {
          if (off < 40) {
            lkv[row][off] = wq * 256 + t * 16 + g * 4 + r;
            lpv[row][off] = __builtin_amdgcn_exp2f((S[t][r] - m) * C2);
          }
          ++off;
        }
      }
  }
  __syncthreads();

  // ---- PV: row = tid>>4 (0..31), d-chunk = (tid&15)*4
  {
    const int prow = tid >> 4;
    const int d4 = (tid & 15) * 4;
    int c = lcnt[prow]; c = c > 40 ? 40 : c;
    const float Zr = (pZ[0][prow] + pZ[1][prow]) + (pZ[2][prow] + pZ[3][prow]);
    float a0 = 0.f, a1 = 0.f, a2 = 0.f, a3 = 0.f, ps = 0.f;
    const float* vbase = vb + (size_t)(b * SKVB) * DE + h * DH + d4;
    for (int e = 0; e < c; ++e) {
      const int kv = lkv[prow][e];
      const float p = lpv[prow][e];
      ps += p;
      const float4 vv = *(const float4*)(vbase + (size_t)kv * DE);
      a0 = fmaf(p, vv.x, a0); a1 = fmaf(p, vv.y, a1);
      a2 = fmaf(p, vv.z, a2); a3 = fmaf(p, vv.w, a3);
    }
    const float inv = 1.0f / (ps + 1e-8f * Zr);
    f16 o[4] = {(f16)(a0 * inv), (f16)(a1 * inv), (f16)(a2 * inv), (f16)(a3 * inv)};
    *(uint2*)(ob + (size_t)(b * SQB + qt * TQ + prow) * DE + h * DH + d4) = *(const uint2*)o;
  }
}

// ---------------------------------------------------------------------------
extern "C" void kernel_launch(void* const* d_in, const int* in_sizes, int n_in,
                              void* d_out, int out_size, void* d_ws, size_t ws_size,
                              hipStream_t stream) {
  const float* x  = (const float*)d_in[0];
  const float* y  = (const float*)d_in[1];
  const float* wq = (const float*)d_in[2];
  const float* bq = (const float*)d_in[3];
  const float* wk = (const float*)d_in[4];
  const float* bk = (const float*)d_in[5];
  const float* wv = (const float*)d_in[6];
  const float* bv = (const float*)d_in[7];
  const float* wo = (const float*)d_in[8];
  const float* bo = (const float*)d_in[9];
  float* out = (float*)d_out;

  char* ws = (char*)d_ws;
  const size_t MiB = 1048576;

  f16* xh  = (f16*)(ws);                       // 16 MiB
  f16* xl  = (f16*)(ws + 16 * MiB);            // 16
  f16* yh  = (f16*)(ws + 32 * MiB);            // 12
  f16* yl  = (f16*)(ws + 44 * MiB);            // 12
  f16* qh  = (f16*)(ws + 56 * MiB);            // 16
  f16* ql  = (f16*)(ws + 72 * MiB);            // 16
  f16* kh  = (f16*)(ws + 88 * MiB);            // 8
  f16* kl  = (f16*)(ws + 96 * MiB);            // 8
  float* v = (float*)(ws + 104 * MiB);         // 16 (f32)
  f16* ao  = (f16*)(ws + 120 * MiB);           // 16
  f16* wqh = (f16*)(ws + 136 * MiB);
  f16* wql = (f16*)(ws + 136 * MiB + 524288);
  f16* wkh = (f16*)(ws + 137 * MiB);
  f16* wkl = (f16*)(ws + 137 * MiB + 786432);
  f16* wvh = (f16*)(ws + 138 * MiB + 524288);
  f16* wvl = (f16*)(ws + 139 * MiB + 262144);
  f16* woh = (f16*)(ws + 140 * MiB);
  f16* wol = (f16*)(ws + 140 * MiB + 524288);

  dim3 blk(256);
  const float WS = 2048.0f, IWS = 1.0f / 2048.0f;

  split_f16<<<dim3(8192), blk, 0, stream>>>(x, xh, xl, 2097152, 1.0f);
  split_f16<<<dim3(6144), blk, 0, stream>>>(y, yh, yl, 1572864, 1.0f);
  split_f16<<<dim3(256),  blk, 0, stream>>>(wq, wqh, wql, 65536, WS);
  split_f16<<<dim3(384),  blk, 0, stream>>>(wk, wkh, wkl, 98304, WS);
  split_f16<<<dim3(384),  blk, 0, stream>>>(wv, wvh, wvl, 98304, 1.0f);
  split_f16<<<dim3(256),  blk, 0, stream>>>(wo, woh, wol, 65536, 1.0f);

  // Q-proj -> split pair scaled x8  (q_true * 0.125 * 64)
  gemm_f16<3, 1><<<dim3(4, 128), blk, 0, stream>>>(xh, xl, wqh, wql, bq,
      nullptr, qh, ql, 16384, 512, 512, IWS, 8.0f);
  // K-proj -> split pair scaled x64
  gemm_f16<3, 1><<<dim3(4, 64), blk, 0, stream>>>(yh, yl, wkh, wkl, bk,
      nullptr, kh, kl, 8192, 512, 768, IWS, 64.0f);
  // V-proj -> f32
  gemm_f16<1, 0><<<dim3(4, 64), blk, 0, stream>>>(yh, nullptr, wvh, nullptr, bv,
      v, nullptr, nullptr, 8192, 512, 768, 1.0f, 1.0f);

  attn_v6<<<dim3(4096), dim3(512), 0, stream>>>(qh, ql, kh, kl, v, ao);

  // O-proj
  gemm_f16<1, 0><<<dim3(4, 128), blk, 0, stream>>>(ao, nullptr, woh, nullptr, bo,
      out, nullptr, nullptr, 16384, 512, 512, 1.0f, 1.0f);
}

// Round 8
// 404.250 us; speedup vs baseline: 1.1379x; 1.1379x over previous
//
#include <hip/hip_runtime.h>
#include <cstdint>
#include <cmath>

#define DH 64
#define SQB 2048
#define SKVB 1024
#define DE 512

typedef _Float16 f16;
typedef _Float16 f16x8 __attribute__((ext_vector_type(8)));
typedef float f32x4 __attribute__((ext_vector_type(4)));

// ---------------------------------------------------------------------------
// Split fp32 -> (hi, lo) fp16 pair, optional pre-scale.
// ---------------------------------------------------------------------------
__global__ __launch_bounds__(256)
void split_f16(const float* __restrict__ in, f16* __restrict__ hi,
               f16* __restrict__ lo, int n4, float scale) {
  const int i = blockIdx.x * 256 + threadIdx.x;
  if (i >= n4) return;
  float4 v = ((const float4*)in)[i];
  v.x *= scale; v.y *= scale; v.z *= scale; v.w *= scale;
  f16 h0 = (f16)v.x, h1 = (f16)v.y, h2 = (f16)v.z, h3 = (f16)v.w;
  f16 l0 = (f16)(v.x - (float)h0), l1 = (f16)(v.y - (float)h1);
  f16 l2 = (f16)(v.z - (float)h2), l3 = (f16)(v.w - (float)h3);
  f16 hb[4] = {h0, h1, h2, h3};
  f16 lb[4] = {l0, l1, l2, l3};
  ((uint2*)hi)[i] = *(const uint2*)hb;
  ((uint2*)lo)[i] = *(const uint2*)lb;
}

// ---------------------------------------------------------------------------
// MFMA f16 GEMM (validated R4/R5 core). OUT=0: C fp32. OUT=1: split-f16 pair.
// ---------------------------------------------------------------------------
template <int NSPLIT, int OUT>
__global__ __launch_bounds__(256, 2)
void gemm_f16(const f16* __restrict__ Ah, const f16* __restrict__ Al,
              const f16* __restrict__ Wh, const f16* __restrict__ Wl,
              const float* __restrict__ bias, float* __restrict__ C,
              f16* __restrict__ Ch, f16* __restrict__ Cl,
              int M, int N, int K, float inv, float oscale) {
  __shared__ f16 smem[(NSPLIT == 3 ? 4 : 2) * 4096];
  f16* As  = smem;
  f16* Als = (NSPLIT == 3) ? smem + 4096 : nullptr;
  f16* Ws  = smem + (NSPLIT == 3 ? 8192 : 4096);
  f16* Wls = (NSPLIT == 3) ? smem + 12288 : nullptr;

  const int tid = threadIdx.x;
  const int w = tid >> 6;
  const int l = tid & 63;
  const int wm = w >> 1, wn = w & 1;
  const int m0 = blockIdx.y * 128;
  const int n0 = blockIdx.x * 128;

  const int srow = tid >> 2;
  const int schk = tid & 3;
  const f16* pA  = Ah + (size_t)(m0 + srow) * K + schk * 8;
  const f16* pW  = Wh + (size_t)(n0 + srow) * K + schk * 8;
  const f16* pAl = (NSPLIT == 3) ? Al + (size_t)(m0 + srow) * K + schk * 8 : nullptr;
  const f16* pWl = (NSPLIT == 3) ? Wl + (size_t)(n0 + srow) * K + schk * 8 : nullptr;
  const size_t rowskip = (size_t)64 * K;

  const int d0 = srow * 32 + ((schk ^ (srow & 3)) * 8);
  const int fbase = (l & 15) * 32 + (((l >> 4) ^ (l & 3)) * 8);
  const int fA = wm * 2048 + fbase;
  const int fW = wn * 2048 + fbase;

  f32x4 acc[4][4] = {};
  uint4 rA0, rA1, rW0, rW1, rAl0, rAl1, rWl0, rWl1;

  rA0 = *(const uint4*)(pA);            rA1 = *(const uint4*)(pA + rowskip);
  rW0 = *(const uint4*)(pW);            rW1 = *(const uint4*)(pW + rowskip);
  if constexpr (NSPLIT == 3) {
    rAl0 = *(const uint4*)(pAl);        rAl1 = *(const uint4*)(pAl + rowskip);
    rWl0 = *(const uint4*)(pWl);        rWl1 = *(const uint4*)(pWl + rowskip);
  }

  for (int k0 = 0; k0 < K; k0 += 32) {
    __syncthreads();
    *(uint4*)&As[d0] = rA0;  *(uint4*)&As[d0 + 2048] = rA1;
    *(uint4*)&Ws[d0] = rW0;  *(uint4*)&Ws[d0 + 2048] = rW1;
    if constexpr (NSPLIT == 3) {
      *(uint4*)&Als[d0] = rAl0;  *(uint4*)&Als[d0 + 2048] = rAl1;
      *(uint4*)&Wls[d0] = rWl0;  *(uint4*)&Wls[d0 + 2048] = rWl1;
    }
    __syncthreads();

    if (k0 + 32 < K) {
      rA0 = *(const uint4*)(pA + k0 + 32);  rA1 = *(const uint4*)(pA + rowskip + k0 + 32);
      rW0 = *(const uint4*)(pW + k0 + 32);  rW1 = *(const uint4*)(pW + rowskip + k0 + 32);
      if constexpr (NSPLIT == 3) {
        rAl0 = *(const uint4*)(pAl + k0 + 32); rAl1 = *(const uint4*)(pAl + rowskip + k0 + 32);
        rWl0 = *(const uint4*)(pWl + k0 + 32); rWl1 = *(const uint4*)(pWl + rowskip + k0 + 32);
      }
    }

    f16x8 ah[4], wh[4], al[4], wl[4];
#pragma unroll
    for (int i = 0; i < 4; ++i) ah[i] = *(const f16x8*)&As[fA + i * 512];
#pragma unroll
    for (int j = 0; j < 4; ++j) wh[j] = *(const f16x8*)&Ws[fW + j * 512];
    if constexpr (NSPLIT == 3) {
#pragma unroll
      for (int i = 0; i < 4; ++i) al[i] = *(const f16x8*)&Als[fA + i * 512];
#pragma unroll
      for (int j = 0; j < 4; ++j) wl[j] = *(const f16x8*)&Wls[fW + j * 512];
    }

#pragma unroll
    for (int i = 0; i < 4; ++i)
#pragma unroll
      for (int j = 0; j < 4; ++j)
        acc[i][j] = __builtin_amdgcn_mfma_f32_16x16x32_f16(ah[i], wh[j], acc[i][j], 0, 0, 0);
    if constexpr (NSPLIT == 3) {
#pragma unroll
      for (int i = 0; i < 4; ++i)
#pragma unroll
        for (int j = 0; j < 4; ++j)
          acc[i][j] = __builtin_amdgcn_mfma_f32_16x16x32_f16(ah[i], wl[j], acc[i][j], 0, 0, 0);
#pragma unroll
      for (int i = 0; i < 4; ++i)
#pragma unroll
        for (int j = 0; j < 4; ++j)
          acc[i][j] = __builtin_amdgcn_mfma_f32_16x16x32_f16(al[i], wh[j], acc[i][j], 0, 0, 0);
    }
  }

  const int rr = (l >> 4) * 4;
  const int cc = l & 15;
#pragma unroll
  for (int j = 0; j < 4; ++j) {
    const int n = n0 + wn * 64 + j * 16 + cc;
    const float bv = bias[n];
#pragma unroll
    for (int i = 0; i < 4; ++i) {
      const int m = m0 + wm * 64 + i * 16 + rr;
#pragma unroll
      for (int r = 0; r < 4; ++r) {
        const float val = acc[i][j][r] * inv + bv;
        if constexpr (OUT == 0) {
          C[(size_t)(m + r) * N + n] = val;
        } else {
          const float sv = val * oscale;
          const f16 hh = (f16)sv;
          const f16 ll = (f16)(sv - (float)hh);
          Ch[(size_t)(m + r) * N + n] = hh;
          Cl[(size_t)(m + r) * N + n] = ll;
        }
      }
    }
  }
}

// ---------------------------------------------------------------------------
// Fused sparse attention v7: v5 semantics, 8 waves / 512 thr, kv EIGHTH per
// wave. S[8] (32 AGPR) + ~62 VGPR -> ~5 waves/SIMD (occupancy lever).
// S[t][r] = s_raw[q=l&15][kv = w*128 + t*16 + (l>>4)*4 + r], s_raw=4096*s.
// ---------------------------------------------------------------------------
__global__ __launch_bounds__(512, 4)
void attn_v7(const f16* __restrict__ qhb, const f16* __restrict__ qlb,
             const f16* __restrict__ khb, const f16* __restrict__ klb,
             const float* __restrict__ vb, f16* __restrict__ ob) {
  __shared__ float pM[8][16], pZ[8][16], pH[8][16], pC[8][16];
  __shared__ int cnt[32][16];          // [group w*4+g][row]
  __shared__ int lkv[16][40];
  __shared__ float lpv[16][40];
  __shared__ int lcnt[16];

  const int phys = blockIdx.x;
  const int bid = (phys & 7) * 1024 + (phys >> 3);   // XCD-pinned, bijective
  const int qt = bid & 127;
  const int h  = (bid >> 7) & 7;
  const int b  = bid >> 10;
  const int tid = threadIdx.x;
  const int w = tid >> 6;              // 0..7 : kv eighth
  const int l = tid & 63;
  const int q16 = l & 15;
  const int g = l >> 4;

  // ---- Q fragments (B operand) — identical across waves
  const size_t qoff = (size_t)(b * SQB + qt * 16 + q16) * DE + h * DH + g * 8;
  const f16x8 qf_h0 = *(const f16x8*)(qhb + qoff);
  const f16x8 qf_h1 = *(const f16x8*)(qhb + qoff + 32);
  const f16x8 qf_l0 = *(const f16x8*)(qlb + qoff);
  const f16x8 qf_l1 = *(const f16x8*)(qlb + qoff + 32);

  // ---- K pointers (A operand): wave w owns kv [128w, 128w+128)
  const size_t koff = (size_t)(b * SKVB + w * 128 + q16) * DE + h * DH + g * 8;
  const f16* kp  = khb + koff;
  const f16* klp = klb + koff;

  f32x4 S[8];
#pragma unroll
  for (int i = 0; i < 8; ++i) S[i] = (f32x4){0.f, 0.f, 0.f, 0.f};

  float mx = -INFINITY;
  f16x8 ka0 = *(const f16x8*)(kp);
  f16x8 ka1 = *(const f16x8*)(kp + 32);
  f16x8 kb0 = *(const f16x8*)(klp);
  f16x8 kb1 = *(const f16x8*)(klp + 32);
#pragma unroll
  for (int t = 0; t < 8; ++t) {
    f16x8 na0, na1, nb0, nb1;
    if (t < 7) {                       // next 16-kv tile: +16 rows * 512
      na0 = *(const f16x8*)(kp + 8192);
      na1 = *(const f16x8*)(kp + 8192 + 32);
      nb0 = *(const f16x8*)(klp + 8192);
      nb1 = *(const f16x8*)(klp + 8192 + 32);
      kp += 8192; klp += 8192;
    }
    // two independent 3-chains, folded (halves dep latency)
    f32x4 sb = (f32x4){0.f, 0.f, 0.f, 0.f};
    S[t] = __builtin_amdgcn_mfma_f32_16x16x32_f16(ka0, qf_h0, S[t], 0, 0, 0);
    sb   = __builtin_amdgcn_mfma_f32_16x16x32_f16(ka1, qf_h1, sb,   0, 0, 0);
    S[t] = __builtin_amdgcn_mfma_f32_16x16x32_f16(ka0, qf_l0, S[t], 0, 0, 0);
    sb   = __builtin_amdgcn_mfma_f32_16x16x32_f16(ka1, qf_l1, sb,   0, 0, 0);
    S[t] = __builtin_amdgcn_mfma_f32_16x16x32_f16(kb0, qf_h0, S[t], 0, 0, 0);
    sb   = __builtin_amdgcn_mfma_f32_16x16x32_f16(kb1, qf_h1, sb,   0, 0, 0);
    S[t][0] += sb[0]; S[t][1] += sb[1]; S[t][2] += sb[2]; S[t][3] += sb[3];
    mx = fmaxf(mx, fmaxf(fmaxf(S[t][0], S[t][1]), fmaxf(S[t][2], S[t][3])));
    if (t < 7) { ka0 = na0; ka1 = na1; kb0 = nb0; kb1 = nb1; }
  }

  // ---- P1: block row max
  mx = fmaxf(mx, __shfl_xor(mx, 16));
  mx = fmaxf(mx, __shfl_xor(mx, 32));
  if (g == 0) pM[w][q16] = mx;
  __syncthreads();
  float m = pM[0][q16];
#pragma unroll
  for (int i = 1; i < 8; ++i) m = fmaxf(m, pM[i][q16]);

  // ---- P2: Z, H, count(s==m); S stays raw
  const float C2 = 1.44269504f / 4096.0f;
  float Zl = 0.f, Hl = 0.f;
  int cl = 0;
#pragma unroll
  for (int t = 0; t < 8; ++t)
#pragma unroll
    for (int r = 0; r < 4; ++r) {
      const float sv = S[t][r] - m;
      const float p = __builtin_amdgcn_exp2f(sv * C2);
      Zl += p;
      Hl = fmaf(p, sv, Hl);
      cl += (S[t][r] == m) ? 1 : 0;
    }
  cnt[w * 4 + g][q16] = cl;
  float clf = (float)cl;
  Zl += __shfl_xor(Zl, 16); Zl += __shfl_xor(Zl, 32);
  Hl += __shfl_xor(Hl, 16); Hl += __shfl_xor(Hl, 32);
  clf += __shfl_xor(clf, 16); clf += __shfl_xor(clf, 32);
  if (g == 0) { pZ[w][q16] = Zl; pH[w][q16] = Hl; pC[w][q16] = clf; }
  __syncthreads();

  float Z = 0.f, Hraw = 0.f, c1 = 0.f;
#pragma unroll
  for (int i = 0; i < 8; ++i) { Z += pZ[i][q16]; Hraw += pH[i][q16]; c1 += pC[i][q16]; }
  const float E = __logf(Z) - (Hraw * (1.0f / 4096.0f)) / Z;
  int tk = (int)(32.0f * (1.0f - E));
  tk = tk < 1 ? 1 : (tk > 32 ? 32 : tk);

  float thr = m, cur = m, rem = (float)tk;
  bool pend = !(c1 >= rem);
  const bool rowSlow = pend;
  if (pend) rem -= c1;

  // ---- slow path (rare; identical row-pend pattern in every wave)
  unsigned long long bal = __ballot(pend);
  if (bal != 0ull) {
    int pass = 0;
    while (bal != 0ull && pass < 40) {
      ++pass;
      float lmx = -INFINITY;
#pragma unroll
      for (int t = 0; t < 8; ++t)
#pragma unroll
        for (int r = 0; r < 4; ++r) {
          const float s = S[t][r];
          lmx = (s < cur) ? fmaxf(lmx, s) : lmx;
        }
      lmx = fmaxf(lmx, __shfl_xor(lmx, 16));
      lmx = fmaxf(lmx, __shfl_xor(lmx, 32));
      if (g == 0) pM[w][q16] = lmx;
      __syncthreads();
      float cand = pM[0][q16];
#pragma unroll
      for (int i = 1; i < 8; ++i) cand = fmaxf(cand, pM[i][q16]);
      float cf = 0.f;
#pragma unroll
      for (int t = 0; t < 8; ++t)
#pragma unroll
        for (int r = 0; r < 4; ++r) cf += (S[t][r] == cand) ? 1.f : 0.f;
      cf += __shfl_xor(cf, 16); cf += __shfl_xor(cf, 32);
      if (g == 0) pC[w][q16] = cf;
      __syncthreads();
      float c2 = 0.f;
#pragma unroll
      for (int i = 0; i < 8; ++i) c2 += pC[i][q16];
      if (pend) {
        if (c2 >= rem) { thr = cand; pend = false; }
        else { rem -= c2; cur = cand; }
      }
      bal = __ballot(pend);
    }
    if (rowSlow) {
      int ns = 0;
#pragma unroll
      for (int t = 0; t < 8; ++t)
#pragma unroll
        for (int r = 0; r < 4; ++r) ns += (S[t][r] >= thr) ? 1 : 0;
      cnt[w * 4 + g][q16] = ns;
    }
    __syncthreads();
  }

  // ---- append selected (kv, p) per row, deterministic group order
  {
    int off = 0;
    const int me = w * 4 + g;
#pragma unroll
    for (int gi = 0; gi < 31; ++gi)
      if (gi < me) off += cnt[gi][q16];
    const int nsel = cnt[me][q16];
    if (me == 31) lcnt[q16] = off + nsel;
#pragma unroll
    for (int t = 0; t < 8; ++t)
#pragma unroll
      for (int r = 0; r < 4; ++r) {
        if (S[t][r] >= thr) {
          if (off < 40) {
            lkv[q16][off] = w * 128 + t * 16 + g * 4 + r;
            lpv[q16][off] = __builtin_amdgcn_exp2f((S[t][r] - m) * C2);
          }
          ++off;
        }
      }
  }
  __syncthreads();

  // ---- PV: row = tid>>5 (0..15), 32 lanes/row, float2 d-chunks
  {
    const int prow = tid >> 5;
    const int d2 = (tid & 31) * 2;
    int c = lcnt[prow]; c = c > 40 ? 40 : c;
    float Zr = 0.f;
#pragma unroll
    for (int i = 0; i < 8; ++i) Zr += pZ[i][prow];
    float a0 = 0.f, a1 = 0.f, ps = 0.f;
    const float* vbase = vb + (size_t)(b * SKVB) * DE + h * DH + d2;
    for (int e = 0; e < c; ++e) {
      const int kv = lkv[prow][e];
      const float p = lpv[prow][e];
      ps += p;
      const float2 vv = *(const float2*)(vbase + (size_t)kv * DE);
      a0 = fmaf(p, vv.x, a0); a1 = fmaf(p, vv.y, a1);
    }
    const float inv = 1.0f / (ps + 1e-8f * Zr);
    f16 o[2] = {(f16)(a0 * inv), (f16)(a1 * inv)};
    *(uint*)(ob + (size_t)(b * SQB + qt * 16 + prow) * DE + h * DH + d2) = *(const uint*)o;
  }
}

// ---------------------------------------------------------------------------
extern "C" void kernel_launch(void* const* d_in, const int* in_sizes, int n_in,
                              void* d_out, int out_size, void* d_ws, size_t ws_size,
                              hipStream_t stream) {
  const float* x  = (const float*)d_in[0];
  const float* y  = (const float*)d_in[1];
  const float* wq = (const float*)d_in[2];
  const float* bq = (const float*)d_in[3];
  const float* wk = (const float*)d_in[4];
  const float* bk = (const float*)d_in[5];
  const float* wv = (const float*)d_in[6];
  const float* bv = (const float*)d_in[7];
  const float* wo = (const float*)d_in[8];
  const float* bo = (const float*)d_in[9];
  float* out = (float*)d_out;

  char* ws = (char*)d_ws;
  const size_t MiB = 1048576;

  f16* xh  = (f16*)(ws);                       // 16 MiB
  f16* xl  = (f16*)(ws + 16 * MiB);            // 16
  f16* yh  = (f16*)(ws + 32 * MiB);            // 12
  f16* yl  = (f16*)(ws + 44 * MiB);            // 12
  f16* qh  = (f16*)(ws + 56 * MiB);            // 16
  f16* ql  = (f16*)(ws + 72 * MiB);            // 16
  f16* kh  = (f16*)(ws + 88 * MiB);            // 8
  f16* kl  = (f16*)(ws + 96 * MiB);            // 8
  float* v = (float*)(ws + 104 * MiB);         // 16 (f32)
  f16* ao  = (f16*)(ws + 120 * MiB);           // 16
  f16* wqh = (f16*)(ws + 136 * MiB);
  f16* wql = (f16*)(ws + 136 * MiB + 524288);
  f16* wkh = (f16*)(ws + 137 * MiB);
  f16* wkl = (f16*)(ws + 137 * MiB + 786432);
  f16* wvh = (f16*)(ws + 138 * MiB + 524288);
  f16* wvl = (f16*)(ws + 139 * MiB + 262144);
  f16* woh = (f16*)(ws + 140 * MiB);
  f16* wol = (f16*)(ws + 140 * MiB + 524288);

  dim3 blk(256);
  const float WS = 2048.0f, IWS = 1.0f / 2048.0f;

  split_f16<<<dim3(8192), blk, 0, stream>>>(x, xh, xl, 2097152, 1.0f);
  split_f16<<<dim3(6144), blk, 0, stream>>>(y, yh, yl, 1572864, 1.0f);
  split_f16<<<dim3(256),  blk, 0, stream>>>(wq, wqh, wql, 65536, WS);
  split_f16<<<dim3(384),  blk, 0, stream>>>(wk, wkh, wkl, 98304, WS);
  split_f16<<<dim3(384),  blk, 0, stream>>>(wv, wvh, wvl, 98304, 1.0f);
  split_f16<<<dim3(256),  blk, 0, stream>>>(wo, woh, wol, 65536, 1.0f);

  // Q-proj -> split pair scaled x8  (q_true * 0.125 * 64)
  gemm_f16<3, 1><<<dim3(4, 128), blk, 0, stream>>>(xh, xl, wqh, wql, bq,
      nullptr, qh, ql, 16384, 512, 512, IWS, 8.0f);
  // K-proj -> split pair scaled x64
  gemm_f16<3, 1><<<dim3(4, 64), blk, 0, stream>>>(yh, yl, wkh, wkl, bk,
      nullptr, kh, kl, 8192, 512, 768, IWS, 64.0f);
  // V-proj -> f32
  gemm_f16<1, 0><<<dim3(4, 64), blk, 0, stream>>>(yh, nullptr, wvh, nullptr, bv,
      v, nullptr, nullptr, 8192, 512, 768, 1.0f, 1.0f);

  attn_v7<<<dim3(8192), dim3(512), 0, stream>>>(qh, ql, kh, kl, v, ao);

  // O-proj
  gemm_f16<1, 0><<<dim3(4, 128), blk, 0, stream>>>(ao, nullptr, woh, nullptr, bo,
      out, nullptr, nullptr, 16384, 512, 512, 1.0f, 1.0f);
}

// Round 9
// 381.115 us; speedup vs baseline: 1.2070x; 1.0607x over previous
//
#include <hip/hip_runtime.h>
#include <cstdint>
#include <cmath>

#define DH 64
#define SQB 2048
#define SKVB 1024
#define DE 512

typedef _Float16 f16;
typedef _Float16 f16x8 __attribute__((ext_vector_type(8)));
typedef float f32x4 __attribute__((ext_vector_type(4)));
typedef float f32x16 __attribute__((ext_vector_type(16)));

#define MFMA32(A, B, C) __builtin_amdgcn_mfma_f32_32x32x16_f16(A, B, C, 0, 0, 0)

// ---------------------------------------------------------------------------
// Split fp32 -> (hi, lo) fp16 pair, optional pre-scale.
// ---------------------------------------------------------------------------
__global__ __launch_bounds__(256)
void split_f16(const float* __restrict__ in, f16* __restrict__ hi,
               f16* __restrict__ lo, int n4, float scale) {
  const int i = blockIdx.x * 256 + threadIdx.x;
  if (i >= n4) return;
  float4 v = ((const float4*)in)[i];
  v.x *= scale; v.y *= scale; v.z *= scale; v.w *= scale;
  f16 h0 = (f16)v.x, h1 = (f16)v.y, h2 = (f16)v.z, h3 = (f16)v.w;
  f16 l0 = (f16)(v.x - (float)h0), l1 = (f16)(v.y - (float)h1);
  f16 l2 = (f16)(v.z - (float)h2), l3 = (f16)(v.w - (float)h3);
  f16 hb[4] = {h0, h1, h2, h3};
  f16 lb[4] = {l0, l1, l2, l3};
  ((uint2*)hi)[i] = *(const uint2*)hb;
  ((uint2*)lo)[i] = *(const uint2*)lb;
}

// ---------------------------------------------------------------------------
// MFMA f16 GEMM (validated R4/R5 core). OUT=0: C fp32. OUT=1: split-f16 pair.
// ---------------------------------------------------------------------------
template <int NSPLIT, int OUT>
__global__ __launch_bounds__(256, 2)
void gemm_f16(const f16* __restrict__ Ah, const f16* __restrict__ Al,
              const f16* __restrict__ Wh, const f16* __restrict__ Wl,
              const float* __restrict__ bias, float* __restrict__ C,
              f16* __restrict__ Ch, f16* __restrict__ Cl,
              int M, int N, int K, float inv, float oscale) {
  __shared__ f16 smem[(NSPLIT == 3 ? 4 : 2) * 4096];
  f16* As  = smem;
  f16* Als = (NSPLIT == 3) ? smem + 4096 : nullptr;
  f16* Ws  = smem + (NSPLIT == 3 ? 8192 : 4096);
  f16* Wls = (NSPLIT == 3) ? smem + 12288 : nullptr;

  const int tid = threadIdx.x;
  const int w = tid >> 6;
  const int l = tid & 63;
  const int wm = w >> 1, wn = w & 1;
  const int m0 = blockIdx.y * 128;
  const int n0 = blockIdx.x * 128;

  const int srow = tid >> 2;
  const int schk = tid & 3;
  const f16* pA  = Ah + (size_t)(m0 + srow) * K + schk * 8;
  const f16* pW  = Wh + (size_t)(n0 + srow) * K + schk * 8;
  const f16* pAl = (NSPLIT == 3) ? Al + (size_t)(m0 + srow) * K + schk * 8 : nullptr;
  const f16* pWl = (NSPLIT == 3) ? Wl + (size_t)(n0 + srow) * K + schk * 8 : nullptr;
  const size_t rowskip = (size_t)64 * K;

  const int d0 = srow * 32 + ((schk ^ (srow & 3)) * 8);
  const int fbase = (l & 15) * 32 + (((l >> 4) ^ (l & 3)) * 8);
  const int fA = wm * 2048 + fbase;
  const int fW = wn * 2048 + fbase;

  f32x4 acc[4][4] = {};
  uint4 rA0, rA1, rW0, rW1, rAl0, rAl1, rWl0, rWl1;

  rA0 = *(const uint4*)(pA);            rA1 = *(const uint4*)(pA + rowskip);
  rW0 = *(const uint4*)(pW);            rW1 = *(const uint4*)(pW + rowskip);
  if constexpr (NSPLIT == 3) {
    rAl0 = *(const uint4*)(pAl);        rAl1 = *(const uint4*)(pAl + rowskip);
    rWl0 = *(const uint4*)(pWl);        rWl1 = *(const uint4*)(pWl + rowskip);
  }

  for (int k0 = 0; k0 < K; k0 += 32) {
    __syncthreads();
    *(uint4*)&As[d0] = rA0;  *(uint4*)&As[d0 + 2048] = rA1;
    *(uint4*)&Ws[d0] = rW0;  *(uint4*)&Ws[d0 + 2048] = rW1;
    if constexpr (NSPLIT == 3) {
      *(uint4*)&Als[d0] = rAl0;  *(uint4*)&Als[d0 + 2048] = rAl1;
      *(uint4*)&Wls[d0] = rWl0;  *(uint4*)&Wls[d0 + 2048] = rWl1;
    }
    __syncthreads();

    if (k0 + 32 < K) {
      rA0 = *(const uint4*)(pA + k0 + 32);  rA1 = *(const uint4*)(pA + rowskip + k0 + 32);
      rW0 = *(const uint4*)(pW + k0 + 32);  rW1 = *(const uint4*)(pW + rowskip + k0 + 32);
      if constexpr (NSPLIT == 3) {
        rAl0 = *(const uint4*)(pAl + k0 + 32); rAl1 = *(const uint4*)(pAl + rowskip + k0 + 32);
        rWl0 = *(const uint4*)(pWl + k0 + 32); rWl1 = *(const uint4*)(pWl + rowskip + k0 + 32);
      }
    }

    f16x8 ah[4], wh[4], al[4], wl[4];
#pragma unroll
    for (int i = 0; i < 4; ++i) ah[i] = *(const f16x8*)&As[fA + i * 512];
#pragma unroll
    for (int j = 0; j < 4; ++j) wh[j] = *(const f16x8*)&Ws[fW + j * 512];
    if constexpr (NSPLIT == 3) {
#pragma unroll
      for (int i = 0; i < 4; ++i) al[i] = *(const f16x8*)&Als[fA + i * 512];
#pragma unroll
      for (int j = 0; j < 4; ++j) wl[j] = *(const f16x8*)&Wls[fW + j * 512];
    }

#pragma unroll
    for (int i = 0; i < 4; ++i)
#pragma unroll
      for (int j = 0; j < 4; ++j)
        acc[i][j] = __builtin_amdgcn_mfma_f32_16x16x32_f16(ah[i], wh[j], acc[i][j], 0, 0, 0);
    if constexpr (NSPLIT == 3) {
#pragma unroll
      for (int i = 0; i < 4; ++i)
#pragma unroll
        for (int j = 0; j < 4; ++j)
          acc[i][j] = __builtin_amdgcn_mfma_f32_16x16x32_f16(ah[i], wl[j], acc[i][j], 0, 0, 0);
#pragma unroll
      for (int i = 0; i < 4; ++i)
#pragma unroll
        for (int j = 0; j < 4; ++j)
          acc[i][j] = __builtin_amdgcn_mfma_f32_16x16x32_f16(al[i], wh[j], acc[i][j], 0, 0, 0);
    }
  }

  const int rr = (l >> 4) * 4;
  const int cc = l & 15;
#pragma unroll
  for (int j = 0; j < 4; ++j) {
    const int n = n0 + wn * 64 + j * 16 + cc;
    const float bv = bias[n];
#pragma unroll
    for (int i = 0; i < 4; ++i) {
      const int m = m0 + wm * 64 + i * 16 + rr;
#pragma unroll
      for (int r = 0; r < 4; ++r) {
        const float val = acc[i][j][r] * inv + bv;
        if constexpr (OUT == 0) {
          C[(size_t)(m + r) * N + n] = val;
        } else {
          const float sv = val * oscale;
          const f16 hh = (f16)sv;
          const f16 ll = (f16)(sv - (float)hh);
          Ch[(size_t)(m + r) * N + n] = hh;
          Cl[(size_t)(m + r) * N + n] = ll;
        }
      }
    }
  }
}

// ---------------------------------------------------------------------------
// Fused sparse attention v8: 32x32x16 MFMA QK^T (split-3 f16), TQ=32 q-rows,
// 8 waves / 512 thr, wave owns kv eighth (128 kv = 4 tiles of 32).
// Lane l owns q-row (l&31); its 64 S values: S[t][r] = s_raw at
// kv = w*128 + t*32 + (r&3) + 8*(r>>2) + 4*(l>>5).  s_raw = 4096*s_true.
// Selection in s-space (v5/v7-validated semantics), exp2 only for Z/H + PV.
// ---------------------------------------------------------------------------
__global__ __launch_bounds__(512)
void attn_v8(const f16* __restrict__ qhb, const f16* __restrict__ qlb,
             const f16* __restrict__ khb, const f16* __restrict__ klb,
             const float* __restrict__ vb, f16* __restrict__ ob) {
  __shared__ float pM[8][32], pZ[8][32], pH[8][32], pC[8][32];
  __shared__ int cnt[16][32];          // [group w*2+(l>>5)][row]
  __shared__ int lkv[32][40];
  __shared__ float lpv[32][40];
  __shared__ int lcnt[32];

  const int phys = blockIdx.x;
  const int bid = (phys & 7) * 512 + (phys >> 3);   // batch -> XCD, bijective
  const int qt = bid & 63;             // 64 q-tiles of 32 rows
  const int h  = (bid >> 6) & 7;
  const int b  = bid >> 9;
  const int tid = threadIdx.x;
  const int w = tid >> 6;              // 0..7 : kv eighth
  const int l = tid & 63;
  const int q5 = l & 31;               // q row / A row
  const int hi5 = l >> 5;              // k-half selector
  const int grp = w * 2 + hi5;         // 0..15 selection group

  // ---- Q B-fragments (persistent): 4 k-steps x {h,l}
  const f16* qbh = qhb + (size_t)(b * SQB + qt * 32 + q5) * DE + h * DH + hi5 * 8;
  const f16* qbl = qlb + (size_t)(b * SQB + qt * 32 + q5) * DE + h * DH + hi5 * 8;
  f16x8 qh_[4], ql_[4];
#pragma unroll
  for (int s = 0; s < 4; ++s) {
    qh_[s] = *(const f16x8*)(qbh + s * 16);
    ql_[s] = *(const f16x8*)(qbl + s * 16);
  }

  // ---- K A-fragment pointers: wave w owns kv [128w, 128w+128)
  const size_t kbase = (size_t)(b * SKVB + w * 128 + q5) * DE + h * DH + hi5 * 8;
  const f16* kph = khb + kbase;
  const f16* kpl = klb + kbase;
  // tile stride: 32 kv rows * 512 = 16384 f16

  f32x16 S[4];
#pragma unroll
  for (int t = 0; t < 4; ++t) S[t] = (f32x16){};

  f16x8 cur[8], nxt[8];
#pragma unroll
  for (int s = 0; s < 4; ++s) {
    cur[s]     = *(const f16x8*)(kph + s * 16);
    cur[s + 4] = *(const f16x8*)(kpl + s * 16);
  }

  float mx = -INFINITY;
#pragma unroll
  for (int t = 0; t < 4; ++t) {
    if (t < 3) {
      const int off = (t + 1) * 16384;
#pragma unroll
      for (int s = 0; s < 4; ++s) {
        nxt[s]     = *(const f16x8*)(kph + off + s * 16);
        nxt[s + 4] = *(const f16x8*)(kpl + off + s * 16);
      }
    }
    // two independent 6-chains
    f32x16 ca = S[t];
    f32x16 cb = (f32x16){};
    ca = MFMA32(cur[0], qh_[0], ca);  cb = MFMA32(cur[1], qh_[1], cb);
    ca = MFMA32(cur[2], qh_[2], ca);  cb = MFMA32(cur[3], qh_[3], cb);
    ca = MFMA32(cur[4], qh_[0], ca);  cb = MFMA32(cur[5], qh_[1], cb);
    ca = MFMA32(cur[6], qh_[2], ca);  cb = MFMA32(cur[7], qh_[3], cb);
    ca = MFMA32(cur[0], ql_[0], ca);  cb = MFMA32(cur[1], ql_[1], cb);
    ca = MFMA32(cur[2], ql_[2], ca);  cb = MFMA32(cur[3], ql_[3], cb);
    S[t] = ca + cb;
#pragma unroll
    for (int r = 0; r < 16; ++r) mx = fmaxf(mx, S[t][r]);
    if (t < 3) {
#pragma unroll
      for (int s = 0; s < 8; ++s) cur[s] = nxt[s];
    }
  }

  // ---- P1: row max (lane pair -> wave partial -> block)
  mx = fmaxf(mx, __shfl_xor(mx, 32));
  if (hi5 == 0) pM[w][q5] = mx;
  __syncthreads();
  float m = pM[0][q5];
#pragma unroll
  for (int i = 1; i < 8; ++i) m = fmaxf(m, pM[i][q5]);

  // ---- P2: Z, H, per-group count(s==m); S stays raw
  const float C2 = 1.44269504f / 4096.0f;
  float Zl = 0.f, Hl = 0.f;
  int cl = 0;
#pragma unroll
  for (int t = 0; t < 4; ++t)
#pragma unroll
    for (int r = 0; r < 16; ++r) {
      const float sv = S[t][r] - m;
      const float p = __builtin_amdgcn_exp2f(sv * C2);
      Zl += p;
      Hl = fmaf(p, sv, Hl);
      cl += (S[t][r] == m) ? 1 : 0;
    }
  cnt[grp][q5] = cl;
  Zl += __shfl_xor(Zl, 32);
  Hl += __shfl_xor(Hl, 32);
  if (hi5 == 0) { pZ[w][q5] = Zl; pH[w][q5] = Hl; }
  __syncthreads();

  float Z = 0.f, Hraw = 0.f;
#pragma unroll
  for (int i = 0; i < 8; ++i) { Z += pZ[i][q5]; Hraw += pH[i][q5]; }
  float c1 = 0.f;
#pragma unroll
  for (int i = 0; i < 16; ++i) c1 += (float)cnt[i][q5];
  const float E = __logf(Z) - (Hraw * (1.0f / 4096.0f)) / Z;
  int tk = (int)(32.0f * (1.0f - E));
  tk = tk < 1 ? 1 : (tk > 32 ? 32 : tk);

  float thr = m, cur2 = m, rem = (float)tk;
  bool pend = !(c1 >= rem);
  const bool rowSlow = pend;
  if (pend) rem -= c1;

  // ---- slow path (rare; identical row-pend pattern in every wave)
  unsigned long long bal = __ballot(pend);
  if (bal != 0ull) {
    int pass = 0;
    while (bal != 0ull && pass < 40) {
      ++pass;
      float lmx = -INFINITY;
#pragma unroll
      for (int t = 0; t < 4; ++t)
#pragma unroll
        for (int r = 0; r < 16; ++r) {
          const float s = S[t][r];
          lmx = (s < cur2) ? fmaxf(lmx, s) : lmx;
        }
      lmx = fmaxf(lmx, __shfl_xor(lmx, 32));
      if (hi5 == 0) pM[w][q5] = lmx;
      __syncthreads();
      float cand = pM[0][q5];
#pragma unroll
      for (int i = 1; i < 8; ++i) cand = fmaxf(cand, pM[i][q5]);
      float cf = 0.f;
#pragma unroll
      for (int t = 0; t < 4; ++t)
#pragma unroll
        for (int r = 0; r < 16; ++r) cf += (S[t][r] == cand) ? 1.f : 0.f;
      cf += __shfl_xor(cf, 32);
      if (hi5 == 0) pC[w][q5] = cf;
      __syncthreads();
      float c2 = 0.f;
#pragma unroll
      for (int i = 0; i < 8; ++i) c2 += pC[i][q5];
      if (pend) {
        if (c2 >= rem) { thr = cand; pend = false; }
        else { rem -= c2; cur2 = cand; }
      }
      bal = __ballot(pend);
    }
    if (rowSlow) {
      int ns = 0;
#pragma unroll
      for (int t = 0; t < 4; ++t)
#pragma unroll
        for (int r = 0; r < 16; ++r) ns += (S[t][r] >= thr) ? 1 : 0;
      cnt[grp][q5] = ns;
    }
    __syncthreads();
  }

  // ---- append selected (kv, p) per row, deterministic group order
  {
    int off = 0;
#pragma unroll
    for (int gi = 0; gi < 15; ++gi)
      if (gi < grp) off += cnt[gi][q5];
    const int nsel = cnt[grp][q5];
    if (grp == 15) lcnt[q5] = off + nsel;
#pragma unroll
    for (int t = 0; t < 4; ++t)
#pragma unroll
      for (int r = 0; r < 16; ++r) {
        if (S[t][r] >= thr) {
          if (off < 40) {
            lkv[q5][off] = w * 128 + t * 32 + (r & 3) + 8 * (r >> 2) + 4 * hi5;
            lpv[q5][off] = __builtin_amdgcn_exp2f((S[t][r] - m) * C2);
          }
          ++off;
        }
      }
  }
  __syncthreads();

  // ---- PV: row = tid>>4 (0..31), 16 lanes/row, float4 d-chunks
  {
    const int prow = tid >> 4;
    const int d4 = (tid & 15) * 4;
    int c = lcnt[prow]; c = c > 40 ? 40 : c;
    float Zr = 0.f;
#pragma unroll
    for (int i = 0; i < 8; ++i) Zr += pZ[i][prow];
    float a0 = 0.f, a1 = 0.f, a2 = 0.f, a3 = 0.f, ps = 0.f;
    const float* vbase = vb + (size_t)(b * SKVB) * DE + h * DH + d4;
    for (int e = 0; e < c; ++e) {
      const int kv = lkv[prow][e];
      const float p = lpv[prow][e];
      ps += p;
      const float4 vv = *(const float4*)(vbase + (size_t)kv * DE);
      a0 = fmaf(p, vv.x, a0); a1 = fmaf(p, vv.y, a1);
      a2 = fmaf(p, vv.z, a2); a3 = fmaf(p, vv.w, a3);
    }
    const float inv = 1.0f / (ps + 1e-8f * Zr);
    f16 o[4] = {(f16)(a0 * inv), (f16)(a1 * inv), (f16)(a2 * inv), (f16)(a3 * inv)};
    *(uint2*)(ob + (size_t)(b * SQB + qt * 32 + prow) * DE + h * DH + d4) = *(const uint2*)o;
  }
}

// ---------------------------------------------------------------------------
extern "C" void kernel_launch(void* const* d_in, const int* in_sizes, int n_in,
                              void* d_out, int out_size, void* d_ws, size_t ws_size,
                              hipStream_t stream) {
  const float* x  = (const float*)d_in[0];
  const float* y  = (const float*)d_in[1];
  const float* wq = (const float*)d_in[2];
  const float* bq = (const float*)d_in[3];
  const float* wk = (const float*)d_in[4];
  const float* bk = (const float*)d_in[5];
  const float* wv = (const float*)d_in[6];
  const float* bv = (const float*)d_in[7];
  const float* wo = (const float*)d_in[8];
  const float* bo = (const float*)d_in[9];
  float* out = (float*)d_out;

  char* ws = (char*)d_ws;
  const size_t MiB = 1048576;

  f16* xh  = (f16*)(ws);                       // 16 MiB
  f16* xl  = (f16*)(ws + 16 * MiB);            // 16
  f16* yh  = (f16*)(ws + 32 * MiB);            // 12
  f16* yl  = (f16*)(ws + 44 * MiB);            // 12
  f16* qh  = (f16*)(ws + 56 * MiB);            // 16
  f16* ql  = (f16*)(ws + 72 * MiB);            // 16
  f16* kh  = (f16*)(ws + 88 * MiB);            // 8
  f16* kl  = (f16*)(ws + 96 * MiB);            // 8
  float* v = (float*)(ws + 104 * MiB);         // 16 (f32)
  f16* ao  = (f16*)(ws + 120 * MiB);           // 16
  f16* wqh = (f16*)(ws + 136 * MiB);
  f16* wql = (f16*)(ws + 136 * MiB + 524288);
  f16* wkh = (f16*)(ws + 137 * MiB);
  f16* wkl = (f16*)(ws + 137 * MiB + 786432);
  f16* wvh = (f16*)(ws + 138 * MiB + 524288);
  f16* wvl = (f16*)(ws + 139 * MiB + 262144);
  f16* woh = (f16*)(ws + 140 * MiB);
  f16* wol = (f16*)(ws + 140 * MiB + 524288);

  dim3 blk(256);
  const float WS = 2048.0f, IWS = 1.0f / 2048.0f;

  split_f16<<<dim3(8192), blk, 0, stream>>>(x, xh, xl, 2097152, 1.0f);
  split_f16<<<dim3(6144), blk, 0, stream>>>(y, yh, yl, 1572864, 1.0f);
  split_f16<<<dim3(256),  blk, 0, stream>>>(wq, wqh, wql, 65536, WS);
  split_f16<<<dim3(384),  blk, 0, stream>>>(wk, wkh, wkl, 98304, WS);
  split_f16<<<dim3(384),  blk, 0, stream>>>(wv, wvh, wvl, 98304, 1.0f);
  split_f16<<<dim3(256),  blk, 0, stream>>>(wo, woh, wol, 65536, 1.0f);

  // Q-proj -> split pair scaled x8  (q_true * 0.125 * 64)
  gemm_f16<3, 1><<<dim3(4, 128), blk, 0, stream>>>(xh, xl, wqh, wql, bq,
      nullptr, qh, ql, 16384, 512, 512, IWS, 8.0f);
  // K-proj -> split pair scaled x64
  gemm_f16<3, 1><<<dim3(4, 64), blk, 0, stream>>>(yh, yl, wkh, wkl, bk,
      nullptr, kh, kl, 8192, 512, 768, IWS, 64.0f);
  // V-proj -> f32
  gemm_f16<1, 0><<<dim3(4, 64), blk, 0, stream>>>(yh, nullptr, wvh, nullptr, bv,
      v, nullptr, nullptr, 8192, 512, 768, 1.0f, 1.0f);

  attn_v8<<<dim3(4096), dim3(512), 0, stream>>>(qh, ql, kh, kl, v, ao);

  // O-proj
  gemm_f16<1, 0><<<dim3(4, 128), blk, 0, stream>>>(ao, nullptr, woh, nullptr, bo,
      out, nullptr, nullptr, 16384, 512, 512, 1.0f, 1.0f);
}